// Round 1
// baseline (8385.595 us; speedup 1.0000x reference)
//
#include <hip/hip_runtime.h>
#include <math.h>

#define T_STEPS 64
#define BATCH   64
#define VOCAB   32000
#define EMB     512
#define HID     1024
#define G4      4096   // 4*HID
#define KSPLIT  8

// ---------------------------------------------------------------------------
// Generic fp32 tiled GEMM: C(MxN) = A(MxK) @ B(KxN) [+ bias]
// Block = (16,16) threads, each thread computes TM x TN outputs.
// A staged transposed in LDS so per-kk reads are float4.
// Requires: M % BM == 0, N % BN == 0, K % BK == 0, BM*BK % 1024 == 0,
//           BK*BN % 1024 == 0, TM,TN multiples of 4.
// ---------------------------------------------------------------------------
template<int BM, int BN, int BK, int TM, int TN, bool BIAS>
__launch_bounds__(256)
__global__ void gemm_f32(const float* __restrict__ A, const float* __restrict__ B,
                         const float* __restrict__ bias, float* __restrict__ C,
                         int M, int N, int K) {
    __shared__ float Ast[BK][BM + 4];
    __shared__ float Bs [BK][BN + 4];
    const int tx = threadIdx.x, ty = threadIdx.y;
    const int t  = ty * 16 + tx;
    const int row0 = blockIdx.y * BM;
    const int col0 = blockIdx.x * BN;

    float acc[TM][TN];
#pragma unroll
    for (int i = 0; i < TM; ++i)
#pragma unroll
        for (int j = 0; j < TN; ++j) acc[i][j] = 0.f;

    for (int k0 = 0; k0 < K; k0 += BK) {
#pragma unroll
        for (int i = 0; i < BM * BK / 1024; ++i) {
            int f = t + i * 256;
            int r = (f * 4) / BK, c = (f * 4) % BK;
            const float4 v = *(const float4*)(A + (size_t)(row0 + r) * K + k0 + c);
            Ast[c + 0][r] = v.x; Ast[c + 1][r] = v.y;
            Ast[c + 2][r] = v.z; Ast[c + 3][r] = v.w;
        }
#pragma unroll
        for (int i = 0; i < BK * BN / 1024; ++i) {
            int f = t + i * 256;
            int r = (f * 4) / BN, c = (f * 4) % BN;
            *(float4*)(&Bs[r][c]) = *(const float4*)(B + (size_t)(k0 + r) * N + col0 + c);
        }
        __syncthreads();
#pragma unroll
        for (int kk = 0; kk < BK; ++kk) {
            float a[TM], b[TN];
#pragma unroll
            for (int i = 0; i < TM; i += 4)
                *(float4*)&a[i] = *(const float4*)&Ast[kk][ty * TM + i];
#pragma unroll
            for (int j = 0; j < TN; j += 4)
                *(float4*)&b[j] = *(const float4*)&Bs[kk][tx * TN + j];
#pragma unroll
            for (int i = 0; i < TM; ++i)
#pragma unroll
                for (int j = 0; j < TN; ++j)
                    acc[i][j] = fmaf(a[i], b[j], acc[i][j]);
        }
        __syncthreads();
    }

#pragma unroll
    for (int i = 0; i < TM; ++i) {
        const int r = row0 + ty * TM + i;
#pragma unroll
        for (int j = 0; j < TN; j += 4) {
            const int c = col0 + tx * TN + j;
            float4 v;
            v.x = acc[i][j];     v.y = acc[i][j + 1];
            v.z = acc[i][j + 2]; v.w = acc[i][j + 3];
            if (BIAS) {
                v.x += bias[c];     v.y += bias[c + 1];
                v.z += bias[c + 2]; v.w += bias[c + 3];
            }
            *(float4*)(C + (size_t)r * N + c) = v;
        }
    }
}

// ---------------------------------------------------------------------------
// LSTM step GEMM with split-K: ZP[kc] (64 x 4096) partial of [x,h] @ W
// A row = concat(X[b, 0:Kx] (ldx), H[b, 0:Ktot-Kx] (ldh)).
// Grid: (4096/64 n-tiles, KSPLIT), block (16,16), 64x64 tile, BK=32.
// ---------------------------------------------------------------------------
__launch_bounds__(256)
__global__ void lstm_gemm(const float* __restrict__ X, int ldx, int Kx,
                          const float* __restrict__ H, int ldh,
                          int KC, const float* __restrict__ W,
                          float* __restrict__ ZP) {
    __shared__ float Ast[32][68];
    __shared__ float Bs [32][68];
    const int tx = threadIdx.x, ty = threadIdx.y;
    const int t  = ty * 16 + tx;
    const int col0 = blockIdx.x * 64;
    const int kc   = blockIdx.y;
    const int kbeg = kc * KC;

    float acc[4][4] = {};
    for (int k0 = kbeg; k0 < kbeg + KC; k0 += 32) {
#pragma unroll
        for (int i = 0; i < 2; ++i) {
            int f = t + i * 256;
            int r = f / 8, c = (f * 4) % 32;
            int kg = k0 + c;
            float4 v;
            if (kg < Kx) v = *(const float4*)(X + (size_t)r * ldx + kg);
            else         v = *(const float4*)(H + (size_t)r * ldh + (kg - Kx));
            Ast[c + 0][r] = v.x; Ast[c + 1][r] = v.y;
            Ast[c + 2][r] = v.z; Ast[c + 3][r] = v.w;
        }
#pragma unroll
        for (int i = 0; i < 2; ++i) {
            int f = t + i * 256;
            int r = f / 16, c = (f * 4) % 64;
            *(float4*)(&Bs[r][c]) = *(const float4*)(W + (size_t)(k0 + r) * G4 + col0 + c);
        }
        __syncthreads();
#pragma unroll
        for (int kk = 0; kk < 32; ++kk) {
            float a[4], b[4];
            *(float4*)&a[0] = *(const float4*)&Ast[kk][ty * 4];
            *(float4*)&b[0] = *(const float4*)&Bs[kk][tx * 4];
#pragma unroll
            for (int i = 0; i < 4; ++i)
#pragma unroll
                for (int j = 0; j < 4; ++j)
                    acc[i][j] = fmaf(a[i], b[j], acc[i][j]);
        }
        __syncthreads();
    }
    float* out = ZP + (size_t)kc * 64 * G4;
#pragma unroll
    for (int i = 0; i < 4; ++i) {
        int r = ty * 4 + i;
        float4 v;
        v.x = acc[i][0]; v.y = acc[i][1]; v.z = acc[i][2]; v.w = acc[i][3];
        *(float4*)(out + (size_t)r * G4 + col0 + tx * 4) = v;
    }
}

// ---------------------------------------------------------------------------
// Reduce split-K partials + bias, apply LSTM cell activations.
// z cols: [f (0:NN), i (NN:2NN), o (2NN:3NN), g (3NN:4NN)]
// ---------------------------------------------------------------------------
__global__ void lstm_act(const float* __restrict__ ZP, const float* __restrict__ bias,
                         float* __restrict__ c_state, float* __restrict__ h_slot,
                         float* __restrict__ hist) {
    int idx = blockIdx.x * 256 + threadIdx.x;   // 0 .. 65535
    int b = idx >> 10, n = idx & 1023;
    float zf = bias[n], zi = bias[HID + n], zo = bias[2 * HID + n], zg = bias[3 * HID + n];
    for (int kc = 0; kc < KSPLIT; ++kc) {
        const float* zr = ZP + ((size_t)kc * 64 + b) * G4;
        zf += zr[n]; zi += zr[HID + n]; zo += zr[2 * HID + n]; zg += zr[3 * HID + n];
    }
    float f = 1.f / (1.f + expf(-zf));
    float i = 1.f / (1.f + expf(-zi));
    float o = 1.f / (1.f + expf(-zo));
    float g = tanhf(zg);
    float cn = f * c_state[idx] + i * g;
    c_state[idx] = cn;
    float hn = o * tanhf(cn);
    h_slot[(size_t)b * 2048 + n] = hn;   // into hcat (stride 2048)
    hist[idx] = hn;                      // into h0s/h1s history
}

// ---------------------------------------------------------------------------
// gates = sigmoid([h0,h1] @ gates_w); gated = g0*h0 + g1*h1 — one block/row.
// ---------------------------------------------------------------------------
__launch_bounds__(256)
__global__ void gates_gated(const float* __restrict__ h0s, const float* __restrict__ h1s,
                            const float* __restrict__ gw, float* __restrict__ gated) {
    const int r = blockIdx.x;
    const int tid = threadIdx.x;
    const float* h0r = h0s + (size_t)r * HID;
    const float* h1r = h1s + (size_t)r * HID;
    float p0 = 0.f, p1 = 0.f;
    for (int k = tid; k < HID; k += 256) {
        float v0 = h0r[k], v1 = h1r[k];
        p0 += v0 * gw[2 * k]     + v1 * gw[2 * (HID + k)];
        p1 += v0 * gw[2 * k + 1] + v1 * gw[2 * (HID + k) + 1];
    }
#pragma unroll
    for (int off = 32; off; off >>= 1) {
        p0 += __shfl_down(p0, off);
        p1 += __shfl_down(p1, off);
    }
    __shared__ float s0[4], s1[4];
    __shared__ float gg[2];
    if ((tid & 63) == 0) { s0[tid >> 6] = p0; s1[tid >> 6] = p1; }
    __syncthreads();
    if (tid == 0) {
        float a = s0[0] + s0[1] + s0[2] + s0[3];
        float b = s1[0] + s1[1] + s1[2] + s1[3];
        gg[0] = 1.f / (1.f + expf(-a));
        gg[1] = 1.f / (1.f + expf(-b));
    }
    __syncthreads();
    float g0 = gg[0], g1 = gg[1];
    for (int n = tid; n < HID; n += 256)
        gated[(size_t)r * HID + n] = g0 * h0r[n] + g1 * h1r[n];
}

// ---------------------------------------------------------------------------
extern "C" void kernel_launch(void* const* d_in, const int* in_sizes, int n_in,
                              void* d_out, int out_size, void* d_ws, size_t ws_size,
                              hipStream_t stream) {
    const float* inputs = (const float*)d_in[0];   // (64,64,32000)
    const float* embm   = (const float*)d_in[1];   // (32000,512)
    const float* w0     = (const float*)d_in[2];   // (1536,4096)
    const float* b0     = (const float*)d_in[3];   // (4096)
    const float* w1     = (const float*)d_in[4];   // (2048,4096)
    const float* b1     = (const float*)d_in[5];   // (4096)
    const float* gw     = (const float*)d_in[6];   // (2048,2)
    const float* outw   = (const float*)d_in[7];   // (1024,32000)
    const float* outb   = (const float*)d_in[8];   // (32000)
    float* logits = (float*)d_out;                 // (4096,32000)

    float* ws    = (float*)d_ws;
    float* emb   = ws;                    // 4096*512      = 2,097,152
    float* h0s   = emb  + 2097152;        // 4096*1024     = 4,194,304
    float* h1s   = h0s  + 4194304;        // 4,194,304
    float* hcat  = h1s  + 4194304;        // 64*2048       = 131,072
    float* c0    = hcat + 131072;         // 64*1024       = 65,536
    float* c1    = c0   + 65536;          // 65,536
    float* zp    = c1   + 65536;          // 8*64*4096     = 2,097,152
    float* gated = zp   + 2097152;        // 4,194,304

    // zero initial LSTM state (hcat, c0, c1 are contiguous: 262144 floats)
    hipMemsetAsync(hcat, 0, (size_t)262144 * sizeof(float), stream);

    // emb = inputs @ embm : (4096x32000)@(32000x512)
    gemm_f32<64, 64, 32, 4, 4, false>
        <<<dim3(EMB / 64, 4096 / 64), dim3(16, 16), 0, stream>>>(
            inputs, embm, nullptr, emb, 4096, EMB, VOCAB);

    // sequential LSTM: 64 steps x 2 layers
    for (int t = 0; t < T_STEPS; ++t) {
        // layer 0: [e_t, h0] @ w0 ; K = 512 + 1024, KC = 192
        lstm_gemm<<<dim3(G4 / 64, KSPLIT), dim3(16, 16), 0, stream>>>(
            emb + (size_t)t * BATCH * EMB, EMB, EMB, hcat, 2048, 1536 / KSPLIT, w0, zp);
        lstm_act<<<256, 256, 0, stream>>>(zp, b0, c0, hcat, h0s + (size_t)t * BATCH * HID);
        // layer 1: [h0, h1] @ w1 ; K = 2048 (single contiguous source), KC = 256
        lstm_gemm<<<dim3(G4 / 64, KSPLIT), dim3(16, 16), 0, stream>>>(
            hcat, 2048, 2048, hcat, 2048, 2048 / KSPLIT, w1, zp);
        lstm_act<<<256, 256, 0, stream>>>(zp, b1, c1, hcat + HID, h1s + (size_t)t * BATCH * HID);
    }

    // gating
    gates_gated<<<4096, 256, 0, stream>>>(h0s, h1s, gw, gated);

    // logits = gated @ outw + outb : (4096x1024)@(1024x32000)
    gemm_f32<128, 128, 16, 8, 8, true>
        <<<dim3(VOCAB / 128, 4096 / 128), dim3(16, 16), 0, stream>>>(
            gated, outw, outb, logits, 4096, VOCAB, 1024);
}

// Round 2
// 4791.875 us; speedup vs baseline: 1.7500x; 1.7500x over previous
//
#include <hip/hip_runtime.h>
#include <math.h>

typedef __attribute__((ext_vector_type(8))) short bf16x8;
typedef __attribute__((ext_vector_type(4))) float f32x4;

#define T_STEPS 64
#define BATCH   64
#define VOCAB   32000
#define EMB     512
#define HID     1024
#define G4      4096   // 4*HID
#define KSPLIT  8

__device__ __forceinline__ unsigned short f2bf(float x) {
    unsigned u = __builtin_bit_cast(unsigned, x);
    u += 0x7FFFu + ((u >> 16) & 1u);           // RNE
    return (unsigned short)(u >> 16);
}
__device__ __forceinline__ float bf2f(unsigned short h) {
    unsigned u = ((unsigned)h) << 16;
    return __builtin_bit_cast(float, u);
}
__device__ __forceinline__ unsigned pack2(unsigned short a, unsigned short b) {
    return (unsigned)a | ((unsigned)b << 16);
}

// ---------------------------------------------------------------------------
// MFMA GEMM, fp32 in/out, bf16 hi/lo split (3 MFMA per fragment pair).
// A: M x K row-major (lda). B: K x N row-major (ldb) — transposed+converted
// into LDS during staging. C partial per blockIdx.z chunk (ldc = N).
// BM=128 fixed; wave grid NW_M x NW_N, wave tile 64x64.
// ---------------------------------------------------------------------------
template<int BN, int NW_M, int NW_N, bool BIAS>
__launch_bounds__(NW_M * NW_N * 64)
__global__ void gemm_bf16x2(const float* __restrict__ A, const float* __restrict__ B,
                            const float* __restrict__ bias, float* __restrict__ C,
                            int N, int lda, int ldb, int KCHUNK, size_t chunkStride) {
    constexpr int BM = 128;
    constexpr int THREADS = NW_M * NW_N * 64;
    __shared__ unsigned short AhS[BM][40], AlS[BM][40];
    __shared__ unsigned short BhS[BN][40], BlS[BN][40];

    const int tid  = threadIdx.x;
    const int row0 = blockIdx.y * BM;
    const int col0 = blockIdx.x * BN;
    const int kBeg = blockIdx.z * KCHUNK;
    C += (size_t)blockIdx.z * chunkStride;

    const int l  = tid & 63, w = tid >> 6;
    const int wm = w / NW_N, wn = w % NW_N;
    const int lr = l & 15,  lk = l >> 4;
    const int kb = lk * 8;

    f32x4 acc[4][4];
#pragma unroll
    for (int m = 0; m < 4; ++m)
#pragma unroll
        for (int n = 0; n < 4; ++n)
#pragma unroll
            for (int r = 0; r < 4; ++r) acc[m][n][r] = 0.f;

    constexpr int A_F4 = BM * 32 / (4 * THREADS);
    constexpr int B_UN = 4 * BN / THREADS;

    for (int k0 = 0; k0 < KCHUNK; k0 += 32) {
        // ---- stage A tile (BM x 32): convert to h/l planes ----
#pragma unroll
        for (int i = 0; i < A_F4; ++i) {
            int f = tid + i * THREADS;
            int r = f >> 3, k4 = (f & 7) << 2;
            float4 v = *(const float4*)(A + (size_t)(row0 + r) * lda + kBeg + k0 + k4);
            unsigned short h0 = f2bf(v.x), h1 = f2bf(v.y), h2 = f2bf(v.z), h3 = f2bf(v.w);
            uint2 hp; hp.x = pack2(h0, h1); hp.y = pack2(h2, h3);
            uint2 lp;
            lp.x = pack2(f2bf(v.x - bf2f(h0)), f2bf(v.y - bf2f(h1)));
            lp.y = pack2(f2bf(v.z - bf2f(h2)), f2bf(v.w - bf2f(h3)));
            *(uint2*)&AhS[r][k4] = hp;
            *(uint2*)&AlS[r][k4] = lp;
        }
        // ---- stage B tile (32 x BN) transposed: BhS[n][k] = bf16(B[k][n]) ----
#pragma unroll
        for (int i = 0; i < B_UN; ++i) {
            int u  = tid + i * THREADS;
            int kq = u & 7, np = u >> 3;
            int n  = np * 2, k = kq * 4;
            const float* bp = B + (size_t)(kBeg + k0 + k) * ldb + col0 + n;
            float2 r0 = *(const float2*)bp;
            float2 r1 = *(const float2*)(bp + ldb);
            float2 r2 = *(const float2*)(bp + 2 * (size_t)ldb);
            float2 r3 = *(const float2*)(bp + 3 * (size_t)ldb);
            {
                unsigned short h0 = f2bf(r0.x), h1 = f2bf(r1.x), h2 = f2bf(r2.x), h3 = f2bf(r3.x);
                uint2 hp; hp.x = pack2(h0, h1); hp.y = pack2(h2, h3);
                uint2 lp;
                lp.x = pack2(f2bf(r0.x - bf2f(h0)), f2bf(r1.x - bf2f(h1)));
                lp.y = pack2(f2bf(r2.x - bf2f(h2)), f2bf(r3.x - bf2f(h3)));
                *(uint2*)&BhS[n][k] = hp;
                *(uint2*)&BlS[n][k] = lp;
            }
            {
                unsigned short h0 = f2bf(r0.y), h1 = f2bf(r1.y), h2 = f2bf(r2.y), h3 = f2bf(r3.y);
                uint2 hp; hp.x = pack2(h0, h1); hp.y = pack2(h2, h3);
                uint2 lp;
                lp.x = pack2(f2bf(r0.y - bf2f(h0)), f2bf(r1.y - bf2f(h1)));
                lp.y = pack2(f2bf(r2.y - bf2f(h2)), f2bf(r3.y - bf2f(h3)));
                *(uint2*)&BhS[n + 1][k] = hp;
                *(uint2*)&BlS[n + 1][k] = lp;
            }
        }
        __syncthreads();
        // ---- fragments + MFMA ----
        bf16x8 ah[4], al[4], bh[4], bl[4];
#pragma unroll
        for (int m = 0; m < 4; ++m) {
            ah[m] = *(const bf16x8*)&AhS[wm * 64 + m * 16 + lr][kb];
            al[m] = *(const bf16x8*)&AlS[wm * 64 + m * 16 + lr][kb];
        }
#pragma unroll
        for (int n = 0; n < 4; ++n) {
            bh[n] = *(const bf16x8*)&BhS[wn * 64 + n * 16 + lr][kb];
            bl[n] = *(const bf16x8*)&BlS[wn * 64 + n * 16 + lr][kb];
        }
#pragma unroll
        for (int m = 0; m < 4; ++m)
#pragma unroll
            for (int n = 0; n < 4; ++n) {
                acc[m][n] = __builtin_amdgcn_mfma_f32_16x16x32_bf16(ah[m], bh[n], acc[m][n], 0, 0, 0);
                acc[m][n] = __builtin_amdgcn_mfma_f32_16x16x32_bf16(al[m], bh[n], acc[m][n], 0, 0, 0);
                acc[m][n] = __builtin_amdgcn_mfma_f32_16x16x32_bf16(ah[m], bl[n], acc[m][n], 0, 0, 0);
            }
        __syncthreads();
    }

    // ---- epilogue: C/D layout col=lane&15, row=(lane>>4)*4+reg ----
#pragma unroll
    for (int n = 0; n < 4; ++n) {
        int col = col0 + wn * 64 + n * 16 + lr;
        float bv = BIAS ? bias[col] : 0.f;
#pragma unroll
        for (int m = 0; m < 4; ++m) {
            int rbase = row0 + wm * 64 + m * 16 + lk * 4;
#pragma unroll
            for (int r = 0; r < 4; ++r)
                C[(size_t)(rbase + r) * N + col] = acc[m][n][r] + bv;
        }
    }
}

// sum 4 split-K partials
__global__ void reduce4(const float* __restrict__ zp, float* __restrict__ out, size_t cs) {
    size_t i = ((size_t)blockIdx.x * 256 + threadIdx.x) * 4;
    float4 a = *(const float4*)(zp + i);
    float4 b = *(const float4*)(zp + cs + i);
    float4 c = *(const float4*)(zp + 2 * cs + i);
    float4 d = *(const float4*)(zp + 3 * cs + i);
    a.x += b.x + c.x + d.x; a.y += b.y + c.y + d.y;
    a.z += b.z + c.z + d.z; a.w += b.w + c.w + d.w;
    *(float4*)(out + i) = a;
}

// ---------------------------------------------------------------------------
// LSTM step GEMM with split-K (fp32 vector) — unchanged from round 0.
// ---------------------------------------------------------------------------
__launch_bounds__(256)
__global__ void lstm_gemm(const float* __restrict__ X, int ldx, int Kx,
                          const float* __restrict__ H, int ldh,
                          int KC, const float* __restrict__ W,
                          float* __restrict__ ZP) {
    __shared__ float Ast[32][68];
    __shared__ float Bs [32][68];
    const int tx = threadIdx.x, ty = threadIdx.y;
    const int t  = ty * 16 + tx;
    const int col0 = blockIdx.x * 64;
    const int kc   = blockIdx.y;
    const int kbeg = kc * KC;

    float acc[4][4] = {};
    for (int k0 = kbeg; k0 < kbeg + KC; k0 += 32) {
#pragma unroll
        for (int i = 0; i < 2; ++i) {
            int f = t + i * 256;
            int r = f / 8, c = (f * 4) % 32;
            int kg = k0 + c;
            float4 v;
            if (kg < Kx) v = *(const float4*)(X + (size_t)r * ldx + kg);
            else         v = *(const float4*)(H + (size_t)r * ldh + (kg - Kx));
            Ast[c + 0][r] = v.x; Ast[c + 1][r] = v.y;
            Ast[c + 2][r] = v.z; Ast[c + 3][r] = v.w;
        }
#pragma unroll
        for (int i = 0; i < 2; ++i) {
            int f = t + i * 256;
            int r = f / 16, c = (f * 4) % 64;
            *(float4*)(&Bs[r][c]) = *(const float4*)(W + (size_t)(k0 + r) * G4 + col0 + c);
        }
        __syncthreads();
#pragma unroll
        for (int kk = 0; kk < 32; ++kk) {
            float a[4], b[4];
            *(float4*)&a[0] = *(const float4*)&Ast[kk][ty * 4];
            *(float4*)&b[0] = *(const float4*)&Bs[kk][tx * 4];
#pragma unroll
            for (int i = 0; i < 4; ++i)
#pragma unroll
                for (int j = 0; j < 4; ++j)
                    acc[i][j] = fmaf(a[i], b[j], acc[i][j]);
        }
        __syncthreads();
    }
    float* out = ZP + (size_t)kc * 64 * G4;
#pragma unroll
    for (int i = 0; i < 4; ++i) {
        int r = ty * 4 + i;
        float4 v;
        v.x = acc[i][0]; v.y = acc[i][1]; v.z = acc[i][2]; v.w = acc[i][3];
        *(float4*)(out + (size_t)r * G4 + col0 + tx * 4) = v;
    }
}

__global__ void lstm_act(const float* __restrict__ ZP, const float* __restrict__ bias,
                         float* __restrict__ c_state, float* __restrict__ h_slot,
                         float* __restrict__ hist) {
    int idx = blockIdx.x * 256 + threadIdx.x;   // 0 .. 65535
    int b = idx >> 10, n = idx & 1023;
    float zf = bias[n], zi = bias[HID + n], zo = bias[2 * HID + n], zg = bias[3 * HID + n];
    for (int kc = 0; kc < KSPLIT; ++kc) {
        const float* zr = ZP + ((size_t)kc * 64 + b) * G4;
        zf += zr[n]; zi += zr[HID + n]; zo += zr[2 * HID + n]; zg += zr[3 * HID + n];
    }
    float f = 1.f / (1.f + expf(-zf));
    float i = 1.f / (1.f + expf(-zi));
    float o = 1.f / (1.f + expf(-zo));
    float g = tanhf(zg);
    float cn = f * c_state[idx] + i * g;
    c_state[idx] = cn;
    float hn = o * tanhf(cn);
    h_slot[(size_t)b * 2048 + n] = hn;
    hist[idx] = hn;
}

__launch_bounds__(256)
__global__ void gates_gated(const float* __restrict__ h0s, const float* __restrict__ h1s,
                            const float* __restrict__ gw, float* __restrict__ gated) {
    const int r = blockIdx.x;
    const int tid = threadIdx.x;
    const float* h0r = h0s + (size_t)r * HID;
    const float* h1r = h1s + (size_t)r * HID;
    float p0 = 0.f, p1 = 0.f;
    for (int k = tid; k < HID; k += 256) {
        float v0 = h0r[k], v1 = h1r[k];
        p0 += v0 * gw[2 * k]     + v1 * gw[2 * (HID + k)];
        p1 += v0 * gw[2 * k + 1] + v1 * gw[2 * (HID + k) + 1];
    }
#pragma unroll
    for (int off = 32; off; off >>= 1) {
        p0 += __shfl_down(p0, off);
        p1 += __shfl_down(p1, off);
    }
    __shared__ float s0[4], s1[4];
    __shared__ float gg[2];
    if ((tid & 63) == 0) { s0[tid >> 6] = p0; s1[tid >> 6] = p1; }
    __syncthreads();
    if (tid == 0) {
        float a = s0[0] + s0[1] + s0[2] + s0[3];
        float b = s1[0] + s1[1] + s1[2] + s1[3];
        gg[0] = 1.f / (1.f + expf(-a));
        gg[1] = 1.f / (1.f + expf(-b));
    }
    __syncthreads();
    float g0 = gg[0], g1 = gg[1];
    for (int n = tid; n < HID; n += 256)
        gated[(size_t)r * HID + n] = g0 * h0r[n] + g1 * h1r[n];
}

// ---------------------------------------------------------------------------
extern "C" void kernel_launch(void* const* d_in, const int* in_sizes, int n_in,
                              void* d_out, int out_size, void* d_ws, size_t ws_size,
                              hipStream_t stream) {
    const float* inputs = (const float*)d_in[0];   // (64,64,32000)
    const float* embm   = (const float*)d_in[1];   // (32000,512)
    const float* w0     = (const float*)d_in[2];   // (1536,4096)
    const float* b0     = (const float*)d_in[3];   // (4096)
    const float* w1     = (const float*)d_in[4];   // (2048,4096)
    const float* b1     = (const float*)d_in[5];   // (4096)
    const float* gw     = (const float*)d_in[6];   // (2048,2)
    const float* outw   = (const float*)d_in[7];   // (1024,32000)
    const float* outb   = (const float*)d_in[8];   // (32000)
    float* logits = (float*)d_out;                 // (4096,32000)

    float* ws    = (float*)d_ws;
    float* emb   = ws;                    // 4096*512
    float* h0s   = emb  + 2097152;        // 4096*1024
    float* h1s   = h0s  + 4194304;
    float* hcat  = h1s  + 4194304;        // 64*2048
    float* c0    = hcat + 131072;         // 64*1024
    float* c1    = c0   + 65536;
    float* zp    = c1   + 65536;          // 8*64*4096
    float* gated = zp   + 2097152;        // 4096*1024

    // emb split-K partials live in d_out (free scratch until the final GEMM)
    float* zpEmb = (float*)d_out;         // 4 * 4096*512 floats = 33.5 MB

    hipMemsetAsync(hcat, 0, (size_t)262144 * sizeof(float), stream);

    // emb = inputs @ embm : (4096x32000)@(32000x512), split-K x4
    gemm_bf16x2<256, 2, 4, false>
        <<<dim3(EMB / 256, 4096 / 128, 4), 512, 0, stream>>>(
            inputs, embm, nullptr, zpEmb, EMB, VOCAB, EMB, VOCAB / 4, (size_t)4096 * EMB);
    reduce4<<<2048, 256, 0, stream>>>(zpEmb, emb, (size_t)4096 * EMB);

    // sequential LSTM: 64 steps x 2 layers (fp32, unchanged)
    for (int t = 0; t < T_STEPS; ++t) {
        lstm_gemm<<<dim3(G4 / 64, KSPLIT), dim3(16, 16), 0, stream>>>(
            emb + (size_t)t * BATCH * EMB, EMB, EMB, hcat, 2048, 1536 / KSPLIT, w0, zp);
        lstm_act<<<256, 256, 0, stream>>>(zp, b0, c0, hcat, h0s + (size_t)t * BATCH * HID);
        lstm_gemm<<<dim3(G4 / 64, KSPLIT), dim3(16, 16), 0, stream>>>(
            hcat, 2048, 2048, hcat, 2048, 2048 / KSPLIT, w1, zp);
        lstm_act<<<256, 256, 0, stream>>>(zp, b1, c1, hcat + HID, h1s + (size_t)t * BATCH * HID);
    }

    gates_gated<<<4096, 256, 0, stream>>>(h0s, h1s, gw, gated);

    // logits = gated @ outw + outb : (4096x1024)@(1024x32000)
    gemm_bf16x2<128, 2, 2, true>
        <<<dim3(VOCAB / 128, 4096 / 128, 1), 256, 0, stream>>>(
            gated, outw, outb, logits, VOCAB, HID, VOCAB, HID, 0);
}

// Round 3
// 4665.872 us; speedup vs baseline: 1.7972x; 1.0270x over previous
//
#include <hip/hip_runtime.h>
#include <math.h>

typedef __attribute__((ext_vector_type(8))) short bf16x8;
typedef __attribute__((ext_vector_type(4))) float f32x4;

#define T_STEPS 64
#define BATCH   64
#define VOCAB   32000
#define EMB     512
#define HID     1024
#define G4      4096   // 4*HID

__device__ __forceinline__ unsigned short f2bf(float x) {
    unsigned u = __builtin_bit_cast(unsigned, x);
    u += 0x7FFFu + ((u >> 16) & 1u);           // RNE
    return (unsigned short)(u >> 16);
}
__device__ __forceinline__ float bf2f(unsigned short h) {
    unsigned u = ((unsigned)h) << 16;
    return __builtin_bit_cast(float, u);
}
__device__ __forceinline__ unsigned pack2(unsigned short a, unsigned short b) {
    return (unsigned)a | ((unsigned)b << 16);
}

// ---------------------------------------------------------------------------
// Generic MFMA GEMM, fp32 in/out, bf16 hi/lo split (3 MFMA per fragment pair).
// (unchanged from round 2 — used for emb, z0x precompute, and final logits)
// ---------------------------------------------------------------------------
template<int BN, int NW_M, int NW_N, bool BIAS>
__launch_bounds__(NW_M * NW_N * 64)
__global__ void gemm_bf16x2(const float* __restrict__ A, const float* __restrict__ B,
                            const float* __restrict__ bias, float* __restrict__ C,
                            int N, int lda, int ldb, int KCHUNK, size_t chunkStride) {
    constexpr int BM = 128;
    constexpr int THREADS = NW_M * NW_N * 64;
    __shared__ unsigned short AhS[BM][40], AlS[BM][40];
    __shared__ unsigned short BhS[BN][40], BlS[BN][40];

    const int tid  = threadIdx.x;
    const int row0 = blockIdx.y * BM;
    const int col0 = blockIdx.x * BN;
    const int kBeg = blockIdx.z * KCHUNK;
    C += (size_t)blockIdx.z * chunkStride;

    const int l  = tid & 63, w = tid >> 6;
    const int wm = w / NW_N, wn = w % NW_N;
    const int lr = l & 15,  lk = l >> 4;
    const int kb = lk * 8;

    f32x4 acc[4][4];
#pragma unroll
    for (int m = 0; m < 4; ++m)
#pragma unroll
        for (int n = 0; n < 4; ++n)
#pragma unroll
            for (int r = 0; r < 4; ++r) acc[m][n][r] = 0.f;

    constexpr int A_F4 = BM * 32 / (4 * THREADS);
    constexpr int B_UN = 4 * BN / THREADS;

    for (int k0 = 0; k0 < KCHUNK; k0 += 32) {
#pragma unroll
        for (int i = 0; i < A_F4; ++i) {
            int f = tid + i * THREADS;
            int r = f >> 3, k4 = (f & 7) << 2;
            float4 v = *(const float4*)(A + (size_t)(row0 + r) * lda + kBeg + k0 + k4);
            unsigned short h0 = f2bf(v.x), h1 = f2bf(v.y), h2 = f2bf(v.z), h3 = f2bf(v.w);
            uint2 hp; hp.x = pack2(h0, h1); hp.y = pack2(h2, h3);
            uint2 lp;
            lp.x = pack2(f2bf(v.x - bf2f(h0)), f2bf(v.y - bf2f(h1)));
            lp.y = pack2(f2bf(v.z - bf2f(h2)), f2bf(v.w - bf2f(h3)));
            *(uint2*)&AhS[r][k4] = hp;
            *(uint2*)&AlS[r][k4] = lp;
        }
#pragma unroll
        for (int i = 0; i < B_UN; ++i) {
            int u  = tid + i * THREADS;
            int kq = u & 7, np = u >> 3;
            int n  = np * 2, k = kq * 4;
            const float* bp = B + (size_t)(kBeg + k0 + k) * ldb + col0 + n;
            float2 r0 = *(const float2*)bp;
            float2 r1 = *(const float2*)(bp + ldb);
            float2 r2 = *(const float2*)(bp + 2 * (size_t)ldb);
            float2 r3 = *(const float2*)(bp + 3 * (size_t)ldb);
            {
                unsigned short h0 = f2bf(r0.x), h1 = f2bf(r1.x), h2 = f2bf(r2.x), h3 = f2bf(r3.x);
                uint2 hp; hp.x = pack2(h0, h1); hp.y = pack2(h2, h3);
                uint2 lp;
                lp.x = pack2(f2bf(r0.x - bf2f(h0)), f2bf(r1.x - bf2f(h1)));
                lp.y = pack2(f2bf(r2.x - bf2f(h2)), f2bf(r3.x - bf2f(h3)));
                *(uint2*)&BhS[n][k] = hp;
                *(uint2*)&BlS[n][k] = lp;
            }
            {
                unsigned short h0 = f2bf(r0.y), h1 = f2bf(r1.y), h2 = f2bf(r2.y), h3 = f2bf(r3.y);
                uint2 hp; hp.x = pack2(h0, h1); hp.y = pack2(h2, h3);
                uint2 lp;
                lp.x = pack2(f2bf(r0.y - bf2f(h0)), f2bf(r1.y - bf2f(h1)));
                lp.y = pack2(f2bf(r2.y - bf2f(h2)), f2bf(r3.y - bf2f(h3)));
                *(uint2*)&BhS[n + 1][k] = hp;
                *(uint2*)&BlS[n + 1][k] = lp;
            }
        }
        __syncthreads();
        bf16x8 ah[4], al[4], bh[4], bl[4];
#pragma unroll
        for (int m = 0; m < 4; ++m) {
            ah[m] = *(const bf16x8*)&AhS[wm * 64 + m * 16 + lr][kb];
            al[m] = *(const bf16x8*)&AlS[wm * 64 + m * 16 + lr][kb];
        }
#pragma unroll
        for (int n = 0; n < 4; ++n) {
            bh[n] = *(const bf16x8*)&BhS[wn * 64 + n * 16 + lr][kb];
            bl[n] = *(const bf16x8*)&BlS[wn * 64 + n * 16 + lr][kb];
        }
#pragma unroll
        for (int m = 0; m < 4; ++m)
#pragma unroll
            for (int n = 0; n < 4; ++n) {
                acc[m][n] = __builtin_amdgcn_mfma_f32_16x16x32_bf16(ah[m], bh[n], acc[m][n], 0, 0, 0);
                acc[m][n] = __builtin_amdgcn_mfma_f32_16x16x32_bf16(al[m], bh[n], acc[m][n], 0, 0, 0);
                acc[m][n] = __builtin_amdgcn_mfma_f32_16x16x32_bf16(ah[m], bl[n], acc[m][n], 0, 0, 0);
            }
        __syncthreads();
    }

#pragma unroll
    for (int n = 0; n < 4; ++n) {
        int col = col0 + wn * 64 + n * 16 + lr;
        float bv = BIAS ? bias[col] : 0.f;
#pragma unroll
        for (int m = 0; m < 4; ++m) {
            int rbase = row0 + wm * 64 + m * 16 + lk * 4;
#pragma unroll
            for (int r = 0; r < 4; ++r)
                C[(size_t)(rbase + r) * N + col] = acc[m][n][r] + bv;
        }
    }
}

// sum 4 split-K partials
__global__ void reduce4(const float* __restrict__ zp, float* __restrict__ out, size_t cs) {
    size_t i = ((size_t)blockIdx.x * 256 + threadIdx.x) * 4;
    float4 a = *(const float4*)(zp + i);
    float4 b = *(const float4*)(zp + cs + i);
    float4 c = *(const float4*)(zp + 2 * cs + i);
    float4 d = *(const float4*)(zp + 3 * cs + i);
    a.x += b.x + c.x + d.x; a.y += b.y + c.y + d.y;
    a.z += b.z + c.z + d.z; a.w += b.w + c.w + d.w;
    *(float4*)(out + i) = a;
}

// ---------------------------------------------------------------------------
// Weight preconversion: W (Krows x 4096 fp32, row-major) -> transposed bf16
// hi/lo planes in PACKED fragment layout:
//   for col n, depth k:  g=n>>4, r=n&15, k8=k>>3, ko=k&7
//   off = (g*(Krows>>3) + k8)*128 + r*8 + ko
// so a wave's b-fragment load (16 cols x 8 ks) is one contiguous 1024B chunk.
// ---------------------------------------------------------------------------
__launch_bounds__(256)
__global__ void wconvert(const float* __restrict__ W, unsigned short* __restrict__ Wh,
                         unsigned short* __restrict__ Wl, int Krows) {
    __shared__ float tile[32][33];
    const int k0 = blockIdx.x * 32;
    const int n0 = blockIdx.y * 32;
    const int tid = threadIdx.x;
#pragma unroll
    for (int i = 0; i < 4; ++i) {
        int idx = tid + i * 256;
        int r = idx >> 5, c = idx & 31;          // r = k, c = n
        tile[r][c] = W[(size_t)(k0 + r) * 4096 + n0 + c];
    }
    __syncthreads();
    const int rn = tid >> 3;                      // n offset 0..31
    const int cq = (tid & 7) * 4;                 // k offset 0,4,...,28
    unsigned short h[4], lo[4];
#pragma unroll
    for (int j = 0; j < 4; ++j) {
        float v = tile[cq + j][rn];
        h[j]  = f2bf(v);
        lo[j] = f2bf(v - bf2f(h[j]));
    }
    const int n = n0 + rn;
    const int g = n >> 4, rr = n & 15;
    const int k = k0 + cq;
    const int K8 = Krows >> 3;
    size_t off = ((size_t)g * K8 + (k >> 3)) * 128 + rr * 8 + (k & 7);
    uint2 hp; hp.x = pack2(h[0], h[1]);  hp.y = pack2(h[2], h[3]);
    uint2 lp; lp.x = pack2(lo[0], lo[1]); lp.y = pack2(lo[2], lo[3]);
    *(uint2*)(Wh + off) = hp;
    *(uint2*)(Wl + off) = lp;
}

// ---------------------------------------------------------------------------
// LSTM step GEMM (MFMA, bf16 hi/lo x3): ZP[kg] (64 x 4096) partial of
// A(64 x Acols, lda=2048) @ Wt, weights in packed transposed bf16 planes.
// Grid (64 col-groups, 4 kg). 4 waves/block; wave tile 64 rows x 16 cols.
// ---------------------------------------------------------------------------
__launch_bounds__(256)
__global__ void lstm_gemm_mfma(const float* __restrict__ A, int Acols,
                               const unsigned short* __restrict__ Wh,
                               const unsigned short* __restrict__ Wl,
                               float* __restrict__ ZP) {
    __shared__ unsigned short AhS[64][72], AlS[64][72];   // 64-wide k chunks
    const int tid = threadIdx.x;
    const int cg = blockIdx.x, kg = blockIdx.y;
    const int kchunk = Acols >> 2;                 // per-kg K range
    const int kbase0 = kg * kchunk;
    const int l = tid & 63, w = tid >> 6;
    const int lr = l & 15, lk = l >> 4;

    const int g = cg * 4 + w;                      // 16-col group id
    // per-lane base into packed weight plane (shorts)
    const size_t wbase = (size_t)g * Acols * 16 + lr * 8 + lk * 128;

    f32x4 acc[4];
#pragma unroll
    for (int m = 0; m < 4; ++m)
#pragma unroll
        for (int r = 0; r < 4; ++r) acc[m][r] = 0.f;

    for (int kc = 0; kc < kchunk; kc += 64) {
        const int kb0 = kbase0 + kc;
        // stage A 64x64 fp32 -> hi/lo bf16 planes (1024 float4 / 256 thr)
#pragma unroll
        for (int i = 0; i < 4; ++i) {
            int f = tid + i * 256;
            int r = f >> 4, c4 = (f & 15) << 2;
            float4 v = *(const float4*)(A + (size_t)r * 2048 + kb0 + c4);
            unsigned short h0 = f2bf(v.x), h1 = f2bf(v.y), h2 = f2bf(v.z), h3 = f2bf(v.w);
            uint2 hp; hp.x = pack2(h0, h1); hp.y = pack2(h2, h3);
            uint2 lp;
            lp.x = pack2(f2bf(v.x - bf2f(h0)), f2bf(v.y - bf2f(h1)));
            lp.y = pack2(f2bf(v.z - bf2f(h2)), f2bf(v.w - bf2f(h3)));
            *(uint2*)&AhS[r][c4] = hp;
            *(uint2*)&AlS[r][c4] = lp;
        }
        __syncthreads();
#pragma unroll
        for (int ks = 0; ks < 2; ++ks) {           // two 32-k steps per chunk
            const size_t boff = wbase + (size_t)((kb0 + ks * 32) >> 3) * 128;
            bf16x8 bh = *(const bf16x8*)(Wh + boff);
            bf16x8 bl = *(const bf16x8*)(Wl + boff);
#pragma unroll
            for (int m = 0; m < 4; ++m) {
                bf16x8 ah = *(const bf16x8*)&AhS[m * 16 + lr][ks * 32 + lk * 8];
                bf16x8 al = *(const bf16x8*)&AlS[m * 16 + lr][ks * 32 + lk * 8];
                acc[m] = __builtin_amdgcn_mfma_f32_16x16x32_bf16(ah, bh, acc[m], 0, 0, 0);
                acc[m] = __builtin_amdgcn_mfma_f32_16x16x32_bf16(al, bh, acc[m], 0, 0, 0);
                acc[m] = __builtin_amdgcn_mfma_f32_16x16x32_bf16(ah, bl, acc[m], 0, 0, 0);
            }
        }
        __syncthreads();
    }

    const int col = cg * 64 + w * 16 + lr;
    float* out = ZP + (size_t)kg * 64 * G4 + col;
#pragma unroll
    for (int m = 0; m < 4; ++m)
#pragma unroll
        for (int r = 0; r < 4; ++r)
            out[(size_t)(m * 16 + lk * 4 + r) * G4] = acc[m][r];
}

// ---------------------------------------------------------------------------
// Reduce 4 split-K partials (+ optional precomputed x-part) + bias, LSTM act.
// ---------------------------------------------------------------------------
__launch_bounds__(256)
__global__ void lstm_act4(const float* __restrict__ ZP, const float* __restrict__ xpart,
                          const float* __restrict__ bias,
                          float* __restrict__ c_state, float* __restrict__ h_slot,
                          float* __restrict__ hist) {
    int idx = blockIdx.x * 256 + threadIdx.x;   // 0 .. 65535
    int b = idx >> 10, n = idx & 1023;
    float zf = bias[n], zi = bias[HID + n], zo = bias[2 * HID + n], zg = bias[3 * HID + n];
    if (xpart) {
        const float* xr = xpart + (size_t)b * G4;
        zf += xr[n]; zi += xr[HID + n]; zo += xr[2 * HID + n]; zg += xr[3 * HID + n];
    }
#pragma unroll
    for (int kc = 0; kc < 4; ++kc) {
        const float* zr = ZP + ((size_t)kc * 64 + b) * G4;
        zf += zr[n]; zi += zr[HID + n]; zo += zr[2 * HID + n]; zg += zr[3 * HID + n];
    }
    float f = 1.f / (1.f + expf(-zf));
    float i = 1.f / (1.f + expf(-zi));
    float o = 1.f / (1.f + expf(-zo));
    float g = tanhf(zg);
    float cn = f * c_state[idx] + i * g;
    c_state[idx] = cn;
    float hn = o * tanhf(cn);
    h_slot[(size_t)b * 2048 + n] = hn;
    hist[idx] = hn;
}

__launch_bounds__(256)
__global__ void gates_gated(const float* __restrict__ h0s, const float* __restrict__ h1s,
                            const float* __restrict__ gw, float* __restrict__ gated) {
    const int r = blockIdx.x;
    const int tid = threadIdx.x;
    const float* h0r = h0s + (size_t)r * HID;
    const float* h1r = h1s + (size_t)r * HID;
    float p0 = 0.f, p1 = 0.f;
    for (int k = tid; k < HID; k += 256) {
        float v0 = h0r[k], v1 = h1r[k];
        p0 += v0 * gw[2 * k]     + v1 * gw[2 * (HID + k)];
        p1 += v0 * gw[2 * k + 1] + v1 * gw[2 * (HID + k) + 1];
    }
#pragma unroll
    for (int off = 32; off; off >>= 1) {
        p0 += __shfl_down(p0, off);
        p1 += __shfl_down(p1, off);
    }
    __shared__ float s0[4], s1[4];
    __shared__ float gg[2];
    if ((tid & 63) == 0) { s0[tid >> 6] = p0; s1[tid >> 6] = p1; }
    __syncthreads();
    if (tid == 0) {
        float a = s0[0] + s0[1] + s0[2] + s0[3];
        float b = s1[0] + s1[1] + s1[2] + s1[3];
        gg[0] = 1.f / (1.f + expf(-a));
        gg[1] = 1.f / (1.f + expf(-b));
    }
    __syncthreads();
    float g0 = gg[0], g1 = gg[1];
    for (int n = tid; n < HID; n += 256)
        gated[(size_t)r * HID + n] = g0 * h0r[n] + g1 * h1r[n];
}

// ---------------------------------------------------------------------------
extern "C" void kernel_launch(void* const* d_in, const int* in_sizes, int n_in,
                              void* d_out, int out_size, void* d_ws, size_t ws_size,
                              hipStream_t stream) {
    const float* inputs = (const float*)d_in[0];
    const float* embm   = (const float*)d_in[1];
    const float* w0     = (const float*)d_in[2];   // (1536,4096)
    const float* b0     = (const float*)d_in[3];
    const float* w1     = (const float*)d_in[4];   // (2048,4096)
    const float* b1     = (const float*)d_in[5];
    const float* gw     = (const float*)d_in[6];
    const float* outw   = (const float*)d_in[7];
    const float* outb   = (const float*)d_in[8];
    float* logits = (float*)d_out;

    float* ws    = (float*)d_ws;
    float* emb   = ws;                    // 4096*512
    float* h0s   = emb  + 2097152;        // 4096*1024
    float* h1s   = h0s  + 4194304;
    float* hcat  = h1s  + 4194304;        // 64*2048
    float* c0    = hcat + 131072;         // 64*1024
    float* c1    = c0   + 65536;
    float* zp    = c1   + 65536;          // 4*64*4096 used
    float* gated = zp   + 2097152;        // 4096*1024

    // d_out doubles as scratch until the final GEMM overwrites it with logits:
    float* zpEmb = (float*)d_out;                          // 4*4096*512 f  (33.5MB)
    float* z0x   = (float*)d_out + 16777216;               // 4096*4096 f   (67MB)
    unsigned short* wt0h = (unsigned short*)((float*)d_out + 33554432);  // 4096x1024 bf16
    unsigned short* wt0l = wt0h + 4194304;
    unsigned short* wt1h = wt0l + 4194304;                 // 4096x2048 bf16
    unsigned short* wt1l = wt1h + 8388608;

    hipMemsetAsync(hcat, 0, (size_t)262144 * sizeof(float), stream);

    // emb = inputs @ embm : (4096x32000)@(32000x512), split-K x4
    gemm_bf16x2<256, 2, 4, false>
        <<<dim3(EMB / 256, 4096 / 128, 4), 512, 0, stream>>>(
            inputs, embm, nullptr, zpEmb, EMB, VOCAB, EMB, VOCAB / 4, (size_t)4096 * EMB);
    reduce4<<<2048, 256, 0, stream>>>(zpEmb, emb, (size_t)4096 * EMB);

    // preconvert LSTM weights to packed transposed bf16 hi/lo planes
    wconvert<<<dim3(1024 / 32, 4096 / 32), 256, 0, stream>>>(w0 + (size_t)512 * G4, wt0h, wt0l, 1024);
    wconvert<<<dim3(2048 / 32, 4096 / 32), 256, 0, stream>>>(w1, wt1h, wt1l, 2048);

    // z0x[t] = e_t @ w0[:512,:]  for all t at once: (4096x512)@(512x4096)
    gemm_bf16x2<128, 2, 2, false>
        <<<dim3(G4 / 128, 4096 / 128, 1), 256, 0, stream>>>(
            emb, w0, nullptr, z0x, G4, EMB, G4, EMB, 0);

    // sequential LSTM: 64 steps x 2 layers (MFMA)
    for (int t = 0; t < T_STEPS; ++t) {
        lstm_gemm_mfma<<<dim3(64, 4), 256, 0, stream>>>(hcat, 1024, wt0h, wt0l, zp);
        lstm_act4<<<256, 256, 0, stream>>>(zp, z0x + (size_t)t * 262144, b0, c0,
                                           hcat, h0s + (size_t)t * 65536);
        lstm_gemm_mfma<<<dim3(64, 4), 256, 0, stream>>>(hcat, 2048, wt1h, wt1l, zp);
        lstm_act4<<<256, 256, 0, stream>>>(zp, nullptr, b1, c1,
                                           hcat + HID, h1s + (size_t)t * 65536);
    }

    gates_gated<<<4096, 256, 0, stream>>>(h0s, h1s, gw, gated);

    // logits = gated @ outw + outb : (4096x1024)@(1024x32000)
    gemm_bf16x2<128, 2, 2, true>
        <<<dim3(VOCAB / 128, 4096 / 128, 1), 256, 0, stream>>>(
            gated, outw, outb, logits, VOCAB, HID, VOCAB, HID, 0);
}